// Round 1
// baseline (1912.573 us; speedup 1.0000x reference)
//
#include <hip/hip_runtime.h>
#include <cstdint>
#include <cstddef>

#define B_SZ   4
#define N_PTS  2048
#define KNN    20
#define BN_ROWS (B_SZ * N_PTS)
#define EPSV   1e-5f
#define SLOPEV 0.2f

// ---------------------------------------------------------------- transpose
// x (B,3,N) -> xt (B*N, 3)
__global__ void k_transpose(const float* __restrict__ x, float* __restrict__ xt)
{
    int i = blockIdx.x * 256 + threadIdx.x;
    if (i >= BN_ROWS) return;
    int b = i >> 11, n = i & 2047;
    #pragma unroll
    for (int c = 0; c < 3; ++c)
        xt[i * 3 + c] = x[((b * 3 + c) << 11) + n];
}

// ---------------------------------------------------------------- weight prep
// W (O, 2C) -> Wc (2O, C): rows [0,O)=W1, rows [O,2O)=W2-W1
__global__ void k_prepw(const float* __restrict__ W, float* __restrict__ Wc, int O, int C)
{
    int i = blockIdx.x * 256 + threadIdx.x;
    if (i >= 2 * O * C) return;
    int j = i / C, c = i - j * C;
    float v;
    if (j < O) v = W[j * 2 * C + c];
    else { int jo = j - O; v = W[jo * 2 * C + C + c] - W[jo * 2 * C + c]; }
    Wc[i] = v;
}

// ---------------------------------------------------------------- row norms
__global__ void k_rownorm(const float* __restrict__ xt, int ld, int C, float* __restrict__ xx)
{
    int i = blockIdx.x * 256 + threadIdx.x;
    if (i >= BN_ROWS) return;
    const float* r = xt + (size_t)i * ld;
    float s = 0.f;
    for (int c = 0; c < C; ++c) s = fmaf(r[c], r[c], s);
    xx[i] = s;
}

// ---------------------------------------------------------------- KNN
// block = 256 threads = 4 waves; wave r scans candidate range [r*512,(r+1)*512)
// for 64 queries (one per lane). Local sorted top-20 per (query,range), then
// 4-way merge preferring lower range on ties (matches jax.lax.top_k stability).
template<int C, int TS>
__launch_bounds__(256)
__global__ void k_knn(const float* __restrict__ xt, int ld,
                      const float* __restrict__ xx, int* __restrict__ idx_out)
{
    constexpr int RANGE = N_PTS / 4;
    constexpr int TILE_FLOATS  = 4 * TS * C + 4 * TS;
    constexpr int MERGE_FLOATS = 4 * 64 * KNN * 2;
    constexpr int SMEM_FLOATS  = (TILE_FLOATS > MERGE_FLOATS ? TILE_FLOATS : MERGE_FLOATS);
    __shared__ __align__(16) float smem[SMEM_FLOATS];

    const int b    = blockIdx.y;
    const int tid  = threadIdx.x;
    const int lane = tid & 63;
    const int r    = tid >> 6;
    const int q    = blockIdx.x * 64 + lane;
    const int mbase = r * RANGE;

    float* tile = smem;                  // [4][TS][C]
    float* txx  = smem + 4 * TS * C;     // [4][TS]

    float qf[C];
    {
        const float* qrow = xt + (size_t)(b * N_PTS + q) * ld;
        if constexpr ((C & 3) == 0) {
            #pragma unroll
            for (int c4 = 0; c4 < C / 4; ++c4) {
                float4 v = *(const float4*)(qrow + c4 * 4);
                qf[c4*4+0] = v.x; qf[c4*4+1] = v.y; qf[c4*4+2] = v.z; qf[c4*4+3] = v.w;
            }
        } else {
            #pragma unroll
            for (int c = 0; c < C; ++c) qf[c] = qrow[c];
        }
    }
    const float xxq = xx[b * N_PTS + q];

    float bv[KNN]; int bi[KNN];
    #pragma unroll
    for (int k = 0; k < KNN; ++k) { bv[k] = -INFINITY; bi[k] = 0; }

    for (int t0 = 0; t0 < RANGE; t0 += TS) {
        __syncthreads();
        for (int e = lane; e < TS * C; e += 64) {
            int j = e / C, c = e - j * C;
            tile[(r * TS + j) * C + c] =
                xt[(size_t)(b * N_PTS + mbase + t0 + j) * ld + c];
        }
        for (int j = lane; j < TS; j += 64)
            txx[r * TS + j] = xx[b * N_PTS + mbase + t0 + j];
        __syncthreads();

        for (int j = 0; j < TS; ++j) {
            float dot = 0.f;
            if constexpr ((C & 3) == 0) {
                const float4* t4 = (const float4*)(tile + (r * TS + j) * C);
                #pragma unroll
                for (int c4 = 0; c4 < C / 4; ++c4) {
                    float4 tv = t4[c4];
                    dot = fmaf(qf[c4*4+0], tv.x, dot);
                    dot = fmaf(qf[c4*4+1], tv.y, dot);
                    dot = fmaf(qf[c4*4+2], tv.z, dot);
                    dot = fmaf(qf[c4*4+3], tv.w, dot);
                }
            } else {
                #pragma unroll
                for (int c = 0; c < C; ++c)
                    dot = fmaf(qf[c], tile[(r * TS + j) * C + c], dot);
            }
            float pd = 2.f * dot - xxq - txx[r * TS + j];
            int cand = mbase + t0 + j;
            if (pd > bv[KNN - 1]) {          // strict: earlier index wins ties
                #pragma unroll
                for (int p = KNN - 1; p >= 1; --p) {
                    if (bv[p] < pd) {
                        bool sh = bv[p - 1] < pd;
                        bv[p] = sh ? bv[p - 1] : pd;
                        bi[p] = sh ? bi[p - 1] : cand;
                    }
                }
                if (bv[0] < pd) { bv[0] = pd; bi[0] = cand; }
            }
        }
    }

    __syncthreads();
    float* lv = smem;                                // [4*64][KNN]
    int*   li = (int*)(smem + 4 * 64 * KNN);
    #pragma unroll
    for (int k = 0; k < KNN; ++k) {
        lv[tid * KNN + k] = bv[k];
        li[tid * KNN + k] = bi[k];
    }
    __syncthreads();
    if (tid < 64) {
        // 4-way merge; at pick k, every pointer <= k <= 19, so no OOB reads.
        int p0 = 0, p1 = 0, p2 = 0, p3 = 0;
        int* outp = idx_out + (size_t)(b * N_PTS + blockIdx.x * 64 + tid) * KNN;
        for (int k = 0; k < KNN; ++k) {
            float v0 = lv[(0 * 64 + tid) * KNN + p0];
            float v1 = lv[(1 * 64 + tid) * KNN + p1];
            float v2 = lv[(2 * 64 + tid) * KNN + p2];
            float v3 = lv[(3 * 64 + tid) * KNN + p3];
            int br = 0; float best = v0;
            if (v1 > best) { best = v1; br = 1; }
            if (v2 > best) { best = v2; br = 2; }
            if (v3 > best) { best = v3; br = 3; }
            int sel;
            if      (br == 0) { sel = li[(0*64+tid)*KNN + p0]; ++p0; }
            else if (br == 1) { sel = li[(1*64+tid)*KNN + p1]; ++p1; }
            else if (br == 2) { sel = li[(2*64+tid)*KNN + p2]; ++p2; }
            else              { sel = li[(3*64+tid)*KNN + p3]; ++p3; }
            outp[k] = sel;
        }
    }
}

// ---------------------------------------------------------------- GEMM C = A @ Bw^T
// A: M x K (row stride lda), Bw: Nn x K row-major, C: M x Nn. M=8192, Nn%64==0.
__launch_bounds__(256)
__global__ void k_gemm(const float* __restrict__ A, int lda,
                       const float* __restrict__ Bw,
                       float* __restrict__ C, int Nn, int Kd)
{
    constexpr int LDT = 68;                 // 64 + 4 pad (keeps 16B align, kills worst conflicts)
    __shared__ float As[32 * LDT];
    __shared__ float Bs[32 * LDT];
    const int tx = threadIdx.x & 15;        // n
    const int ty = threadIdx.x >> 4;        // m
    const int m0 = blockIdx.y * 64;
    const int n0 = blockIdx.x * 64;
    float acc[4][4] = {};
    for (int k0 = 0; k0 < Kd; k0 += 32) {
        for (int e = threadIdx.x; e < 64 * 32; e += 256) {
            int kk = e & 31, mm = e >> 5;
            int kg = k0 + kk;
            As[kk * LDT + mm] = (kg < Kd) ? A[(size_t)(m0 + mm) * lda + kg] : 0.f;
        }
        for (int e = threadIdx.x; e < 64 * 32; e += 256) {
            int kk = e & 31, nn = e >> 5;
            int kg = k0 + kk;
            Bs[kk * LDT + nn] = (kg < Kd) ? Bw[(size_t)(n0 + nn) * Kd + kg] : 0.f;
        }
        __syncthreads();
        #pragma unroll
        for (int kk = 0; kk < 32; ++kk) {
            float4 a4 = *(const float4*)&As[kk * LDT + ty * 4];
            float4 b4 = *(const float4*)&Bs[kk * LDT + tx * 4];
            float av[4] = {a4.x, a4.y, a4.z, a4.w};
            float bw[4] = {b4.x, b4.y, b4.z, b4.w};
            #pragma unroll
            for (int i = 0; i < 4; ++i)
                #pragma unroll
                for (int j = 0; j < 4; ++j)
                    acc[i][j] = fmaf(av[i], bw[j], acc[i][j]);
        }
        __syncthreads();
    }
    #pragma unroll
    for (int i = 0; i < 4; ++i) {
        float4 v = make_float4(acc[i][0], acc[i][1], acc[i][2], acc[i][3]);
        *(float4*)&C[(size_t)(m0 + ty * 4 + i) * Nn + n0 + tx * 4] = v;
    }
}

// ---------------------------------------------------------------- gather + stats
// gd (B*N, 2O): g=[:, :O], d=[:, O:]. h[n,k,o] = g[idx[n,k]][o] + d[n][o].
// Emits per-(n,o) max/min over k, and banked channel sum/sumsq of h.
template<int O, int NSEQ>
__launch_bounds__(256)
__global__ void k_gather(const float* __restrict__ gd, const int* __restrict__ idx,
                         float* __restrict__ hmax, float* __restrict__ hmin,
                         float* __restrict__ ssum, float* __restrict__ ssumsq)
{
    constexpr int NPB = 256 / O;
    const int grp = threadIdx.x / O;
    const int o   = threadIdx.x & (O - 1);
    float accS = 0.f, accS2 = 0.f;
    const int rowsPerBlock = NPB * NSEQ;
    for (int s = 0; s < NSEQ; ++s) {
        int row = blockIdx.x * rowsPerBlock + s * NPB + grp;
        const int* ip = idx + (size_t)row * KNN;
        int bbase = (row >> 11) << 11;
        float gmax = -INFINITY, gmin = INFINITY, gs = 0.f, gs2 = 0.f;
        for (int k = 0; k < KNN; ++k) {
            int nb = ip[k];
            float v = gd[(size_t)(bbase + nb) * (2 * O) + o];
            gmax = fmaxf(gmax, v);
            gmin = fminf(gmin, v);
            gs  += v;
            gs2  = fmaf(v, v, gs2);
        }
        float d = gd[(size_t)row * (2 * O) + O + o];
        hmax[(size_t)row * O + o] = gmax + d;
        hmin[(size_t)row * O + o] = gmin + d;
        accS  += gs + (float)KNN * d;
        accS2 += gs2 + 2.f * d * gs + (float)KNN * d * d;
    }
    int bank = blockIdx.x & 63;
    atomicAdd(&ssum[bank * O + o], accS);
    atomicAdd(&ssumsq[bank * O + o], accS2);
}

// ---------------------------------------------------------------- finalize BN stats
// scsh[o] = scale, scsh[1024+o] = shift
__global__ void k_finalize(const float* __restrict__ ssum, const float* __restrict__ ssumsq,
                           const float* __restrict__ gamma, const float* __restrict__ beta,
                           float* __restrict__ scsh, int O, float invM)
{
    int o = threadIdx.x;
    if (o >= O) return;
    float s = 0.f, s2 = 0.f;
    for (int bk = 0; bk < 64; ++bk) { s += ssum[bk * O + o]; s2 += ssumsq[bk * O + o]; }
    float mean = s * invM;
    float var  = fmaf(-mean, mean, s2 * invM);
    float sc   = gamma[o] * rsqrtf(var + EPSV);
    scsh[o]        = sc;
    scsh[1024 + o] = beta[o] - mean * sc;
}

// ---------------------------------------------------------------- normalize + lrelu -> xc slice
template<int O>
__global__ void k_normalize(const float* __restrict__ hmax, const float* __restrict__ hmin,
                            const float* __restrict__ scsh, const float* __restrict__ gamma,
                            float* __restrict__ xcs)
{
    int i = blockIdx.x * 256 + threadIdx.x;
    if (i >= BN_ROWS * O) return;
    int row = i / O, o = i & (O - 1);
    float h = (gamma[o] >= 0.f) ? hmax[i] : hmin[i];   // bn monotone: max/min commute
    float y = fmaf(h, scsh[o], scsh[1024 + o]);
    y = (y >= 0.f) ? y : SLOPEV * y;
    xcs[(size_t)row * 512 + o] = y;
}

// ---------------------------------------------------------------- layer-5 stats (no atomics: 16 banks, 1 writer each)
__global__ void k_stats5(const float* __restrict__ h, float* __restrict__ ssum, float* __restrict__ ssumsq)
{
    int o  = blockIdx.y * 256 + threadIdx.x;
    int r0 = blockIdx.x * 512;
    float s = 0.f, s2 = 0.f;
    for (int r = 0; r < 512; ++r) {
        float v = h[(size_t)(r0 + r) * 1024 + o];
        s += v; s2 = fmaf(v, v, s2);
    }
    ssum[blockIdx.x * 1024 + o]   = s;
    ssumsq[blockIdx.x * 1024 + o] = s2;
}

// ---------------------------------------------------------------- normalize+lrelu + 64-seg max/sum
__global__ void k_seg(const float* __restrict__ h, const float* __restrict__ scsh,
                      float* __restrict__ smax, float* __restrict__ ssumseg)
{
    int f   = blockIdx.y * 256 + threadIdx.x;
    int seg = blockIdx.x;                 // 0..127 (= b*32 + s)
    float sc = scsh[f], sh = scsh[1024 + f];
    float mx = -INFINITY, sm = 0.f;
    int n0 = seg * 64;
    for (int i = 0; i < 64; ++i) {
        float v = fmaf(h[(size_t)(n0 + i) * 1024 + f], sc, sh);
        v = (v >= 0.f) ? v : SLOPEV * v;
        mx = fmaxf(mx, v); sm += v;
    }
    smax[(size_t)seg * 1024 + f]    = mx;
    ssumseg[(size_t)seg * 1024 + f] = sm;
}

// ---------------------------------------------------------------- hierarchical bins (nb=1..32 -> 63 rows)
__global__ void k_combine(const float* __restrict__ smax, const float* __restrict__ ssum,
                          float* __restrict__ bins)
{
    int b = blockIdx.x;
    int f = blockIdx.y * 256 + threadIdx.x;
    float mx[32], sm[32];
    #pragma unroll
    for (int s = 0; s < 32; ++s) {
        mx[s] = smax[(size_t)(b * 32 + s) * 1024 + f];
        sm[s] = ssum[(size_t)(b * 32 + s) * 1024 + f];
    }
    float* bb = bins + (size_t)b * 63 * 1024 + f;
    #pragma unroll
    for (int s = 0; s < 32; ++s) bb[(size_t)(31 + s) * 1024] = mx[s] + sm[s] * (1.f / 64.f);
    #pragma unroll
    for (int s = 0; s < 16; ++s) { mx[s] = fmaxf(mx[2*s], mx[2*s+1]); sm[s] = sm[2*s] + sm[2*s+1]; }
    #pragma unroll
    for (int s = 0; s < 16; ++s) bb[(size_t)(15 + s) * 1024] = mx[s] + sm[s] * (1.f / 128.f);
    #pragma unroll
    for (int s = 0; s < 8; ++s)  { mx[s] = fmaxf(mx[2*s], mx[2*s+1]); sm[s] = sm[2*s] + sm[2*s+1]; }
    #pragma unroll
    for (int s = 0; s < 8; ++s)  bb[(size_t)(7 + s) * 1024] = mx[s] + sm[s] * (1.f / 256.f);
    #pragma unroll
    for (int s = 0; s < 4; ++s)  { mx[s] = fmaxf(mx[2*s], mx[2*s+1]); sm[s] = sm[2*s] + sm[2*s+1]; }
    #pragma unroll
    for (int s = 0; s < 4; ++s)  bb[(size_t)(3 + s) * 1024] = mx[s] + sm[s] * (1.f / 512.f);
    #pragma unroll
    for (int s = 0; s < 2; ++s)  { mx[s] = fmaxf(mx[2*s], mx[2*s+1]); sm[s] = sm[2*s] + sm[2*s+1]; }
    #pragma unroll
    for (int s = 0; s < 2; ++s)  bb[(size_t)(1 + s) * 1024] = mx[s] + sm[s] * (1.f / 1024.f);
    mx[0] = fmaxf(mx[0], mx[1]); sm[0] = sm[0] + sm[1];
    bb[0] = mx[0] + sm[0] * (1.f / 2048.f);
}

// ---------------------------------------------------------------- final projection: out[s][b][o]
__launch_bounds__(256)
__global__ void k_final(const float* __restrict__ bins, const float* __restrict__ Wf,
                        const float* __restrict__ bfeat, float* __restrict__ out)
{
    __shared__ float row[1024];
    int sb = blockIdx.x;             // s*4 + b
    int s = sb >> 2, b = sb & 3;
    for (int e = threadIdx.x; e < 1024; e += 256)
        row[e] = bins[(size_t)(b * 63 + s) * 1024 + e];
    __syncthreads();
    int o = threadIdx.x;
    const float* w = Wf + (size_t)o * 1024;
    float acc = 0.f;
    for (int fb = 0; fb < 1024; fb += 4) {
        float4 w4 = *(const float4*)&w[fb];
        acc = fmaf(row[fb + 0], w4.x, acc);
        acc = fmaf(row[fb + 1], w4.y, acc);
        acc = fmaf(row[fb + 2], w4.z, acc);
        acc = fmaf(row[fb + 3], w4.w, acc);
    }
    out[(size_t)sb * 256 + o] = acc + bfeat[o];
}

// ================================================================ launch
extern "C" void kernel_launch(void* const* d_in, const int* in_sizes, int n_in,
                              void* d_out, int out_size, void* d_ws, size_t ws_size,
                              hipStream_t stream)
{
    const float* x  = (const float*)d_in[0];
    const float* W1 = (const float*)d_in[1];
    const float* g1 = (const float*)d_in[2];
    const float* b1 = (const float*)d_in[3];
    const float* W2 = (const float*)d_in[4];
    const float* g2 = (const float*)d_in[5];
    const float* b2 = (const float*)d_in[6];
    const float* W3 = (const float*)d_in[7];
    const float* g3 = (const float*)d_in[8];
    const float* b3 = (const float*)d_in[9];
    const float* W4 = (const float*)d_in[10];
    const float* g4 = (const float*)d_in[11];
    const float* b4 = (const float*)d_in[12];
    const float* W5 = (const float*)d_in[13];
    const float* g5 = (const float*)d_in[14];
    const float* b5 = (const float*)d_in[15];
    const float* Wf = (const float*)d_in[16];
    const float* bfeat = (const float*)d_in[17];
    float* out = (float*)d_out;
    float* ws  = (float*)d_ws;

    // workspace layout (floats); total = 18,216,960 floats = 72.9 MB
    float* xt1   = ws;                        // 24576
    int*   idx   = (int*)(ws + 24576);        // 163840
    float* xx    = ws + 24576 + 163840;       // 8192
    float* xc    = xx + 8192;                 // 8192*512
    float* hmax  = xc + 4194304;              // 8192*256
    float* hmin  = hmax + 2097152;            // 8192*256
    float* stats = hmin + 2097152;            // 5 * 2 * 64 * 1024
    float* scsh  = stats + 655360;            // 2048
    float* smax  = scsh + 2048;               // 128*1024
    float* ssg   = smax + 131072;             // 128*1024
    float* bins  = ssg + 131072;              // 4*63*1024
    float* wcomb = bins + 258048;             // 512*128 max
    float* big   = wcomb + 65536;             // max(gd 8192*512, h5 8192*1024)

    hipMemsetAsync(stats, 0, 655360 * sizeof(float), stream);

    k_transpose<<<32, 256, 0, stream>>>(x, xt1);

    const float invMk = 1.f / (float)(BN_ROWS * KNN);

    // ------------- layer 1: C=3, O=64, in xt1 (ld 3), out xc[:,0:64)
    {
        float* ss = stats + 0 * 131072;
        k_prepw<<<(2*64*3 + 255)/256, 256, 0, stream>>>(W1, wcomb, 64, 3);
        k_rownorm<<<32, 256, 0, stream>>>(xt1, 3, 3, xx);
        k_knn<3, 128><<<dim3(32, 4), 256, 0, stream>>>(xt1, 3, xx, idx);
        k_gemm<<<dim3(2, 128), 256, 0, stream>>>(xt1, 3, wcomb, big, 128, 3);
        k_gather<64, 8><<<256, 256, 0, stream>>>(big, idx, hmax, hmin, ss, ss + 65536);
        k_finalize<<<1, 64, 0, stream>>>(ss, ss + 65536, g1, b1, scsh, 64, invMk);
        k_normalize<64><<<(BN_ROWS*64 + 255)/256, 256, 0, stream>>>(hmax, hmin, scsh, g1, xc + 0);
    }
    // ------------- layer 2: C=64, O=64, in xc[:,0:64), out xc[:,64:128)
    {
        float* ss = stats + 1 * 131072;
        k_prepw<<<(2*64*64 + 255)/256, 256, 0, stream>>>(W2, wcomb, 64, 64);
        k_rownorm<<<32, 256, 0, stream>>>(xc + 0, 512, 64, xx);
        k_knn<64, 32><<<dim3(32, 4), 256, 0, stream>>>(xc + 0, 512, xx, idx);
        k_gemm<<<dim3(2, 128), 256, 0, stream>>>(xc + 0, 512, wcomb, big, 128, 64);
        k_gather<64, 8><<<256, 256, 0, stream>>>(big, idx, hmax, hmin, ss, ss + 65536);
        k_finalize<<<1, 64, 0, stream>>>(ss, ss + 65536, g2, b2, scsh, 64, invMk);
        k_normalize<64><<<(BN_ROWS*64 + 255)/256, 256, 0, stream>>>(hmax, hmin, scsh, g2, xc + 64);
    }
    // ------------- layer 3: C=64, O=128, in xc[:,64:128), out xc[:,128:256)
    {
        float* ss = stats + 2 * 131072;
        k_prepw<<<(2*128*64 + 255)/256, 256, 0, stream>>>(W3, wcomb, 128, 64);
        k_rownorm<<<32, 256, 0, stream>>>(xc + 64, 512, 64, xx);
        k_knn<64, 32><<<dim3(32, 4), 256, 0, stream>>>(xc + 64, 512, xx, idx);
        k_gemm<<<dim3(4, 128), 256, 0, stream>>>(xc + 64, 512, wcomb, big, 256, 64);
        k_gather<128, 8><<<512, 256, 0, stream>>>(big, idx, hmax, hmin, ss, ss + 65536);
        k_finalize<<<1, 128, 0, stream>>>(ss, ss + 65536, g3, b3, scsh, 128, invMk);
        k_normalize<128><<<(BN_ROWS*128 + 255)/256, 256, 0, stream>>>(hmax, hmin, scsh, g3, xc + 128);
    }
    // ------------- layer 4: C=128, O=256, in xc[:,128:256), out xc[:,256:512)
    {
        float* ss = stats + 3 * 131072;
        k_prepw<<<(2*256*128 + 255)/256, 256, 0, stream>>>(W4, wcomb, 256, 128);
        k_rownorm<<<32, 256, 0, stream>>>(xc + 128, 512, 128, xx);
        k_knn<128, 16><<<dim3(32, 4), 256, 0, stream>>>(xc + 128, 512, xx, idx);
        k_gemm<<<dim3(8, 128), 256, 0, stream>>>(xc + 128, 512, wcomb, big, 512, 128);
        k_gather<256, 8><<<1024, 256, 0, stream>>>(big, idx, hmax, hmin, ss, ss + 65536);
        k_finalize<<<1, 256, 0, stream>>>(ss, ss + 65536, g4, b4, scsh, 256, invMk);
        k_normalize<256><<<(BN_ROWS*256 + 255)/256, 256, 0, stream>>>(hmax, hmin, scsh, g4, xc + 256);
    }
    // ------------- layer 5: h = xc @ W5^T (8192x512 @ 512x1024), BN over rows
    {
        float* ss = stats + 4 * 131072;
        k_gemm<<<dim3(16, 128), 256, 0, stream>>>(xc, 512, W5, big, 1024, 512);
        k_stats5<<<dim3(16, 4), 256, 0, stream>>>(big, ss, ss + 65536);
        k_finalize<<<1, 1024, 0, stream>>>(ss, ss + 65536, g5, b5, scsh, 1024, 1.f / (float)BN_ROWS);
        k_seg<<<dim3(128, 4), 256, 0, stream>>>(big, scsh, smax, ssg);
        k_combine<<<dim3(4, 4), 256, 0, stream>>>(smax, ssg, bins);
        k_final<<<252, 256, 0, stream>>>(bins, Wf, bfeat, out);
    }
}

// Round 2
// 957.394 us; speedup vs baseline: 1.9977x; 1.9977x over previous
//
#include <hip/hip_runtime.h>
#include <cstdint>
#include <cstddef>

#define B_SZ   4
#define N_PTS  2048
#define KNN    20
#define BN_ROWS (B_SZ * N_PTS)
#define EPSV   1e-5f
#define SLOPEV 0.2f

// ---------------------------------------------------------------- transpose
// x (B,3,N) -> xt (B*N, 3)
__global__ void k_transpose(const float* __restrict__ x, float* __restrict__ xt)
{
    int i = blockIdx.x * 256 + threadIdx.x;
    if (i >= BN_ROWS) return;
    int b = i >> 11, n = i & 2047;
    #pragma unroll
    for (int c = 0; c < 3; ++c)
        xt[i * 3 + c] = x[((b * 3 + c) << 11) + n];
}

// ---------------------------------------------------------------- weight prep
// W (O, 2C) -> Wc (2O, C): rows [0,O)=W1, rows [O,2O)=W2-W1
__global__ void k_prepw(const float* __restrict__ W, float* __restrict__ Wc, int O, int C)
{
    int i = blockIdx.x * 256 + threadIdx.x;
    if (i >= 2 * O * C) return;
    int j = i / C, c = i - j * C;
    float v;
    if (j < O) v = W[j * 2 * C + c];
    else { int jo = j - O; v = W[jo * 2 * C + C + c] - W[jo * 2 * C + c]; }
    Wc[i] = v;
}

// ---------------------------------------------------------------- row norms
__global__ void k_rownorm(const float* __restrict__ xt, int ld, int C, float* __restrict__ xx)
{
    int i = blockIdx.x * 256 + threadIdx.x;
    if (i >= BN_ROWS) return;
    const float* r = xt + (size_t)i * ld;
    float s = 0.f;
    for (int c = 0; c < C; ++c) s = fmaf(r[c], r[c], s);
    xx[i] = s;
}

// ---------------------------------------------------------------- distance matrix
// D2[(bl*N + i)*N + j] = 2*dot(x_i,x_j) - xx_i - xx_j   for 2 batches b0+bl.
// fma accumulation k-ascending == k_rownorm order, so diagonal is exactly +0.
__launch_bounds__(256)
__global__ void k_dist(const float* __restrict__ xt, int ld, int b0,
                       const float* __restrict__ xx, float* __restrict__ D2, int Kd)
{
    constexpr int LDT = 68;
    __shared__ float As[32 * LDT];
    __shared__ float Bs[32 * LDT];
    const int tx = threadIdx.x & 15;        // j
    const int ty = threadIdx.x >> 4;        // i
    const int bl = blockIdx.z;
    const int b  = b0 + bl;
    const int i0 = blockIdx.y * 64;
    const int j0 = blockIdx.x * 64;
    const float* Xb = xt + (size_t)b * N_PTS * ld;
    float acc[4][4] = {};
    for (int k0 = 0; k0 < Kd; k0 += 32) {
        for (int e = threadIdx.x; e < 64 * 32; e += 256) {
            int kk = e & 31, mm = e >> 5, kg = k0 + kk;
            As[kk * LDT + mm] = (kg < Kd) ? Xb[(size_t)(i0 + mm) * ld + kg] : 0.f;
        }
        for (int e = threadIdx.x; e < 64 * 32; e += 256) {
            int kk = e & 31, nn = e >> 5, kg = k0 + kk;
            Bs[kk * LDT + nn] = (kg < Kd) ? Xb[(size_t)(j0 + nn) * ld + kg] : 0.f;
        }
        __syncthreads();
        #pragma unroll
        for (int kk = 0; kk < 32; ++kk) {
            float4 a4 = *(const float4*)&As[kk * LDT + ty * 4];
            float4 b4 = *(const float4*)&Bs[kk * LDT + tx * 4];
            float av[4] = {a4.x, a4.y, a4.z, a4.w};
            float bw[4] = {b4.x, b4.y, b4.z, b4.w};
            #pragma unroll
            for (int i = 0; i < 4; ++i)
                #pragma unroll
                for (int j = 0; j < 4; ++j)
                    acc[i][j] = fmaf(av[i], bw[j], acc[i][j]);
        }
        __syncthreads();
    }
    const float* xxb = xx + b * N_PTS;
    float4 xj4 = *(const float4*)&xxb[j0 + tx * 4];
    float xjv[4] = {xj4.x, xj4.y, xj4.z, xj4.w};
    #pragma unroll
    for (int i = 0; i < 4; ++i) {
        float xi = xxb[i0 + ty * 4 + i];
        float4 v;
        v.x = 2.f * acc[i][0] - xi - xjv[0];
        v.y = 2.f * acc[i][1] - xi - xjv[1];
        v.z = 2.f * acc[i][2] - xi - xjv[2];
        v.w = 2.f * acc[i][3] - xi - xjv[3];
        *(float4*)&D2[((size_t)bl * N_PTS + i0 + ty * 4 + i) * N_PTS + j0 + tx * 4] = v;
    }
}

// ---------------------------------------------------------------- top-20 select
// One wave per query. 32 distances/lane in regs; exact 20th-largest via 32-step
// integer bisection on the monotone uint key; ballot-compacted emission.
// Downstream max/sum over k is order-invariant, so set semantics suffice.
__launch_bounds__(256)
__global__ void k_select(const float* __restrict__ D2, int b0, int* __restrict__ idx_out)
{
    const int lane = threadIdx.x & 63;
    const int w    = threadIdx.x >> 6;
    const int qloc = blockIdx.x * 4 + w;          // 0..4095 (2 batches)
    const int bl   = qloc >> 11;
    const int n    = qloc & 2047;
    const float* row = D2 + (size_t)qloc * N_PTS;

    unsigned key[32];
    #pragma unroll
    for (int c = 0; c < 8; ++c) {
        float4 v = *(const float4*)&row[c * 256 + lane * 4];
        float vv[4] = {v.x, v.y, v.z, v.w};
        #pragma unroll
        for (int r = 0; r < 4; ++r) {
            unsigned u = __float_as_uint(vv[r]);
            key[c * 4 + r] = ((int)u >= 0) ? (u | 0x80000000u) : ~u;
        }
    }

    // bisection: T = smallest m with #{key > m} < 20  == 20th-largest key
    unsigned lo = 0u, hi = 0xFFFFFFFFu;
    while (lo < hi) {
        unsigned mid = lo + ((hi - lo) >> 1);
        int cnt = 0;
        #pragma unroll
        for (int e = 0; e < 32; ++e) cnt += (key[e] > mid) ? 1 : 0;
        #pragma unroll
        for (int s = 32; s >= 1; s >>= 1) cnt += __shfl_xor(cnt, s, 64);
        cnt = __builtin_amdgcn_readfirstlane(cnt);
        if (cnt < KNN) hi = mid; else lo = mid + 1;
    }
    const unsigned T = lo;

    int* outp = idx_out + (size_t)((b0 + bl) * N_PTS + n) * KNN;
    const unsigned long long ltmask = (lane == 0) ? 0ull : (~0ull >> (64 - lane));
    int base = 0;
    #pragma unroll
    for (int e = 0; e < 32; ++e) {
        bool p = key[e] > T;
        unsigned long long m = __ballot(p);
        if (p) {
            int pos = base + __popcll(m & ltmask);
            outp[pos] = (e >> 2) * 256 + lane * 4 + (e & 3);
        }
        base += __popcll(m);
    }
    for (int e = 0; e < 32 && base < KNN; ++e) {
        bool p = key[e] == T;
        unsigned long long m = __ballot(p);
        if (p) {
            int pos = base + __popcll(m & ltmask);
            if (pos < KNN) outp[pos] = (e >> 2) * 256 + lane * 4 + (e & 3);
        }
        base += __popcll(m);
    }
}

// ---------------------------------------------------------------- GEMM C = A @ Bw^T
// A: M x K (row stride lda), Bw: Nn x K row-major, C: M x Nn. M=8192, Nn%64==0.
__launch_bounds__(256)
__global__ void k_gemm(const float* __restrict__ A, int lda,
                       const float* __restrict__ Bw,
                       float* __restrict__ C, int Nn, int Kd)
{
    constexpr int LDT = 68;
    __shared__ float As[32 * LDT];
    __shared__ float Bs[32 * LDT];
    const int tx = threadIdx.x & 15;        // n
    const int ty = threadIdx.x >> 4;        // m
    const int m0 = blockIdx.y * 64;
    const int n0 = blockIdx.x * 64;
    float acc[4][4] = {};
    for (int k0 = 0; k0 < Kd; k0 += 32) {
        for (int e = threadIdx.x; e < 64 * 32; e += 256) {
            int kk = e & 31, mm = e >> 5;
            int kg = k0 + kk;
            As[kk * LDT + mm] = (kg < Kd) ? A[(size_t)(m0 + mm) * lda + kg] : 0.f;
        }
        for (int e = threadIdx.x; e < 64 * 32; e += 256) {
            int kk = e & 31, nn = e >> 5;
            int kg = k0 + kk;
            Bs[kk * LDT + nn] = (kg < Kd) ? Bw[(size_t)(n0 + nn) * Kd + kg] : 0.f;
        }
        __syncthreads();
        #pragma unroll
        for (int kk = 0; kk < 32; ++kk) {
            float4 a4 = *(const float4*)&As[kk * LDT + ty * 4];
            float4 b4 = *(const float4*)&Bs[kk * LDT + tx * 4];
            float av[4] = {a4.x, a4.y, a4.z, a4.w};
            float bw[4] = {b4.x, b4.y, b4.z, b4.w};
            #pragma unroll
            for (int i = 0; i < 4; ++i)
                #pragma unroll
                for (int j = 0; j < 4; ++j)
                    acc[i][j] = fmaf(av[i], bw[j], acc[i][j]);
        }
        __syncthreads();
    }
    #pragma unroll
    for (int i = 0; i < 4; ++i) {
        float4 v = make_float4(acc[i][0], acc[i][1], acc[i][2], acc[i][3]);
        *(float4*)&C[(size_t)(m0 + ty * 4 + i) * Nn + n0 + tx * 4] = v;
    }
}

// ---------------------------------------------------------------- gather + stats
// gd (B*N, 2O): g=[:, :O], d=[:, O:]. h[n,k,o] = g[idx[n,k]][o] + d[n][o].
template<int O, int NSEQ>
__launch_bounds__(256)
__global__ void k_gather(const float* __restrict__ gd, const int* __restrict__ idx,
                         float* __restrict__ hmax, float* __restrict__ hmin,
                         float* __restrict__ ssum, float* __restrict__ ssumsq)
{
    constexpr int NPB = 256 / O;
    const int grp = threadIdx.x / O;
    const int o   = threadIdx.x & (O - 1);
    float accS = 0.f, accS2 = 0.f;
    const int rowsPerBlock = NPB * NSEQ;
    for (int s = 0; s < NSEQ; ++s) {
        int row = blockIdx.x * rowsPerBlock + s * NPB + grp;
        const int* ip = idx + (size_t)row * KNN;
        int bbase = (row >> 11) << 11;
        float gmax = -INFINITY, gmin = INFINITY, gs = 0.f, gs2 = 0.f;
        for (int k = 0; k < KNN; ++k) {
            int nb = ip[k];
            float v = gd[(size_t)(bbase + nb) * (2 * O) + o];
            gmax = fmaxf(gmax, v);
            gmin = fminf(gmin, v);
            gs  += v;
            gs2  = fmaf(v, v, gs2);
        }
        float d = gd[(size_t)row * (2 * O) + O + o];
        hmax[(size_t)row * O + o] = gmax + d;
        hmin[(size_t)row * O + o] = gmin + d;
        accS  += gs + (float)KNN * d;
        accS2 += gs2 + 2.f * d * gs + (float)KNN * d * d;
    }
    int bank = blockIdx.x & 63;
    atomicAdd(&ssum[bank * O + o], accS);
    atomicAdd(&ssumsq[bank * O + o], accS2);
}

// ---------------------------------------------------------------- finalize BN stats
__global__ void k_finalize(const float* __restrict__ ssum, const float* __restrict__ ssumsq,
                           const float* __restrict__ gamma, const float* __restrict__ beta,
                           float* __restrict__ scsh, int O, float invM)
{
    int o = threadIdx.x;
    if (o >= O) return;
    float s = 0.f, s2 = 0.f;
    for (int bk = 0; bk < 64; ++bk) { s += ssum[bk * O + o]; s2 += ssumsq[bk * O + o]; }
    float mean = s * invM;
    float var  = fmaf(-mean, mean, s2 * invM);
    float sc   = gamma[o] * rsqrtf(var + EPSV);
    scsh[o]        = sc;
    scsh[1024 + o] = beta[o] - mean * sc;
}

// ---------------------------------------------------------------- normalize + lrelu -> xc slice
template<int O>
__global__ void k_normalize(const float* __restrict__ hmax, const float* __restrict__ hmin,
                            const float* __restrict__ scsh, const float* __restrict__ gamma,
                            float* __restrict__ xcs)
{
    int i = blockIdx.x * 256 + threadIdx.x;
    if (i >= BN_ROWS * O) return;
    int row = i / O, o = i & (O - 1);
    float h = (gamma[o] >= 0.f) ? hmax[i] : hmin[i];
    float y = fmaf(h, scsh[o], scsh[1024 + o]);
    y = (y >= 0.f) ? y : SLOPEV * y;
    xcs[(size_t)row * 512 + o] = y;
}

// ---------------------------------------------------------------- layer-5 stats
__global__ void k_stats5(const float* __restrict__ h, float* __restrict__ ssum, float* __restrict__ ssumsq)
{
    int o  = blockIdx.y * 256 + threadIdx.x;
    int r0 = blockIdx.x * 512;
    float s = 0.f, s2 = 0.f;
    for (int r = 0; r < 512; ++r) {
        float v = h[(size_t)(r0 + r) * 1024 + o];
        s += v; s2 = fmaf(v, v, s2);
    }
    ssum[blockIdx.x * 1024 + o]   = s;
    ssumsq[blockIdx.x * 1024 + o] = s2;
}

// ---------------------------------------------------------------- normalize+lrelu + 64-seg max/sum
__global__ void k_seg(const float* __restrict__ h, const float* __restrict__ scsh,
                      float* __restrict__ smax, float* __restrict__ ssumseg)
{
    int f   = blockIdx.y * 256 + threadIdx.x;
    int seg = blockIdx.x;
    float sc = scsh[f], sh = scsh[1024 + f];
    float mx = -INFINITY, sm = 0.f;
    int n0 = seg * 64;
    for (int i = 0; i < 64; ++i) {
        float v = fmaf(h[(size_t)(n0 + i) * 1024 + f], sc, sh);
        v = (v >= 0.f) ? v : SLOPEV * v;
        mx = fmaxf(mx, v); sm += v;
    }
    smax[(size_t)seg * 1024 + f]    = mx;
    ssumseg[(size_t)seg * 1024 + f] = sm;
}

// ---------------------------------------------------------------- hierarchical bins
__global__ void k_combine(const float* __restrict__ smax, const float* __restrict__ ssum,
                          float* __restrict__ bins)
{
    int b = blockIdx.x;
    int f = blockIdx.y * 256 + threadIdx.x;
    float mx[32], sm[32];
    #pragma unroll
    for (int s = 0; s < 32; ++s) {
        mx[s] = smax[(size_t)(b * 32 + s) * 1024 + f];
        sm[s] = ssum[(size_t)(b * 32 + s) * 1024 + f];
    }
    float* bb = bins + (size_t)b * 63 * 1024 + f;
    #pragma unroll
    for (int s = 0; s < 32; ++s) bb[(size_t)(31 + s) * 1024] = mx[s] + sm[s] * (1.f / 64.f);
    #pragma unroll
    for (int s = 0; s < 16; ++s) { mx[s] = fmaxf(mx[2*s], mx[2*s+1]); sm[s] = sm[2*s] + sm[2*s+1]; }
    #pragma unroll
    for (int s = 0; s < 16; ++s) bb[(size_t)(15 + s) * 1024] = mx[s] + sm[s] * (1.f / 128.f);
    #pragma unroll
    for (int s = 0; s < 8; ++s)  { mx[s] = fmaxf(mx[2*s], mx[2*s+1]); sm[s] = sm[2*s] + sm[2*s+1]; }
    #pragma unroll
    for (int s = 0; s < 8; ++s)  bb[(size_t)(7 + s) * 1024] = mx[s] + sm[s] * (1.f / 256.f);
    #pragma unroll
    for (int s = 0; s < 4; ++s)  { mx[s] = fmaxf(mx[2*s], mx[2*s+1]); sm[s] = sm[2*s] + sm[2*s+1]; }
    #pragma unroll
    for (int s = 0; s < 4; ++s)  bb[(size_t)(3 + s) * 1024] = mx[s] + sm[s] * (1.f / 512.f);
    #pragma unroll
    for (int s = 0; s < 2; ++s)  { mx[s] = fmaxf(mx[2*s], mx[2*s+1]); sm[s] = sm[2*s] + sm[2*s+1]; }
    #pragma unroll
    for (int s = 0; s < 2; ++s)  bb[(size_t)(1 + s) * 1024] = mx[s] + sm[s] * (1.f / 1024.f);
    mx[0] = fmaxf(mx[0], mx[1]); sm[0] = sm[0] + sm[1];
    bb[0] = mx[0] + sm[0] * (1.f / 2048.f);
}

// ---------------------------------------------------------------- final projection
__launch_bounds__(256)
__global__ void k_final(const float* __restrict__ bins, const float* __restrict__ Wf,
                        const float* __restrict__ bfeat, float* __restrict__ out)
{
    __shared__ float row[1024];
    int sb = blockIdx.x;
    int s = sb >> 2, b = sb & 3;
    for (int e = threadIdx.x; e < 1024; e += 256)
        row[e] = bins[(size_t)(b * 63 + s) * 1024 + e];
    __syncthreads();
    int o = threadIdx.x;
    const float* w = Wf + (size_t)o * 1024;
    float acc = 0.f;
    for (int fb = 0; fb < 1024; fb += 4) {
        float4 w4 = *(const float4*)&w[fb];
        acc = fmaf(row[fb + 0], w4.x, acc);
        acc = fmaf(row[fb + 1], w4.y, acc);
        acc = fmaf(row[fb + 2], w4.z, acc);
        acc = fmaf(row[fb + 3], w4.w, acc);
    }
    out[(size_t)sb * 256 + o] = acc + bfeat[o];
}

// ================================================================ launch
extern "C" void kernel_launch(void* const* d_in, const int* in_sizes, int n_in,
                              void* d_out, int out_size, void* d_ws, size_t ws_size,
                              hipStream_t stream)
{
    const float* x  = (const float*)d_in[0];
    const float* W1 = (const float*)d_in[1];
    const float* g1 = (const float*)d_in[2];
    const float* b1 = (const float*)d_in[3];
    const float* W2 = (const float*)d_in[4];
    const float* g2 = (const float*)d_in[5];
    const float* b2 = (const float*)d_in[6];
    const float* W3 = (const float*)d_in[7];
    const float* g3 = (const float*)d_in[8];
    const float* b3 = (const float*)d_in[9];
    const float* W4 = (const float*)d_in[10];
    const float* g4 = (const float*)d_in[11];
    const float* b4 = (const float*)d_in[12];
    const float* W5 = (const float*)d_in[13];
    const float* g5 = (const float*)d_in[14];
    const float* b5 = (const float*)d_in[15];
    const float* Wf = (const float*)d_in[16];
    const float* bfeat = (const float*)d_in[17];
    float* out = (float*)d_out;
    float* ws  = (float*)d_ws;

    // workspace layout (floats) — unchanged from round 1 (72.9 MB total).
    // `big` (8,388,608 floats = 32 MB) triple-duty: D2 (2 batches x N x N),
    // then gd per layer, then h5 — lifetimes are disjoint (serial stream).
    float* xt1   = ws;                        // 24576
    int*   idx   = (int*)(ws + 24576);        // 163840
    float* xx    = ws + 24576 + 163840;       // 8192
    float* xc    = xx + 8192;                 // 8192*512
    float* hmax  = xc + 4194304;              // 8192*256
    float* hmin  = hmax + 2097152;            // 8192*256
    float* stats = hmin + 2097152;            // 5 * 2 * 64 * 1024
    float* scsh  = stats + 655360;            // 2048
    float* smax  = scsh + 2048;               // 128*1024
    float* ssg   = smax + 131072;             // 128*1024
    float* bins  = ssg + 131072;              // 4*63*1024
    float* wcomb = bins + 258048;             // 512*128 max
    float* big   = wcomb + 65536;             // 8,388,608 floats

    hipMemsetAsync(stats, 0, 655360 * sizeof(float), stream);

    k_transpose<<<32, 256, 0, stream>>>(x, xt1);

    const float invMk = 1.f / (float)(BN_ROWS * KNN);

    // ------------- layer 1: C=3, O=64
    {
        float* ss = stats + 0 * 131072;
        k_prepw<<<(2*64*3 + 255)/256, 256, 0, stream>>>(W1, wcomb, 64, 3);
        k_rownorm<<<32, 256, 0, stream>>>(xt1, 3, 3, xx);
        for (int c = 0; c < 2; ++c) {
            k_dist<<<dim3(32, 32, 2), 256, 0, stream>>>(xt1, 3, 2*c, xx, big, 3);
            k_select<<<1024, 256, 0, stream>>>(big, 2*c, idx);
        }
        k_gemm<<<dim3(2, 128), 256, 0, stream>>>(xt1, 3, wcomb, big, 128, 3);
        k_gather<64, 8><<<256, 256, 0, stream>>>(big, idx, hmax, hmin, ss, ss + 65536);
        k_finalize<<<1, 64, 0, stream>>>(ss, ss + 65536, g1, b1, scsh, 64, invMk);
        k_normalize<64><<<(BN_ROWS*64 + 255)/256, 256, 0, stream>>>(hmax, hmin, scsh, g1, xc + 0);
    }
    // ------------- layer 2: C=64, O=64
    {
        float* ss = stats + 1 * 131072;
        k_prepw<<<(2*64*64 + 255)/256, 256, 0, stream>>>(W2, wcomb, 64, 64);
        k_rownorm<<<32, 256, 0, stream>>>(xc + 0, 512, 64, xx);
        for (int c = 0; c < 2; ++c) {
            k_dist<<<dim3(32, 32, 2), 256, 0, stream>>>(xc + 0, 512, 2*c, xx, big, 64);
            k_select<<<1024, 256, 0, stream>>>(big, 2*c, idx);
        }
        k_gemm<<<dim3(2, 128), 256, 0, stream>>>(xc + 0, 512, wcomb, big, 128, 64);
        k_gather<64, 8><<<256, 256, 0, stream>>>(big, idx, hmax, hmin, ss, ss + 65536);
        k_finalize<<<1, 64, 0, stream>>>(ss, ss + 65536, g2, b2, scsh, 64, invMk);
        k_normalize<64><<<(BN_ROWS*64 + 255)/256, 256, 0, stream>>>(hmax, hmin, scsh, g2, xc + 64);
    }
    // ------------- layer 3: C=64, O=128
    {
        float* ss = stats + 2 * 131072;
        k_prepw<<<(2*128*64 + 255)/256, 256, 0, stream>>>(W3, wcomb, 128, 64);
        k_rownorm<<<32, 256, 0, stream>>>(xc + 64, 512, 64, xx);
        for (int c = 0; c < 2; ++c) {
            k_dist<<<dim3(32, 32, 2), 256, 0, stream>>>(xc + 64, 512, 2*c, xx, big, 64);
            k_select<<<1024, 256, 0, stream>>>(big, 2*c, idx);
        }
        k_gemm<<<dim3(4, 128), 256, 0, stream>>>(xc + 64, 512, wcomb, big, 256, 64);
        k_gather<128, 8><<<512, 256, 0, stream>>>(big, idx, hmax, hmin, ss, ss + 65536);
        k_finalize<<<1, 128, 0, stream>>>(ss, ss + 65536, g3, b3, scsh, 128, invMk);
        k_normalize<128><<<(BN_ROWS*128 + 255)/256, 256, 0, stream>>>(hmax, hmin, scsh, g3, xc + 128);
    }
    // ------------- layer 4: C=128, O=256
    {
        float* ss = stats + 3 * 131072;
        k_prepw<<<(2*256*128 + 255)/256, 256, 0, stream>>>(W4, wcomb, 256, 128);
        k_rownorm<<<32, 256, 0, stream>>>(xc + 128, 512, 128, xx);
        for (int c = 0; c < 2; ++c) {
            k_dist<<<dim3(32, 32, 2), 256, 0, stream>>>(xc + 128, 512, 2*c, xx, big, 128);
            k_select<<<1024, 256, 0, stream>>>(big, 2*c, idx);
        }
        k_gemm<<<dim3(8, 128), 256, 0, stream>>>(xc + 128, 512, wcomb, big, 512, 128);
        k_gather<256, 8><<<1024, 256, 0, stream>>>(big, idx, hmax, hmin, ss, ss + 65536);
        k_finalize<<<1, 256, 0, stream>>>(ss, ss + 65536, g4, b4, scsh, 256, invMk);
        k_normalize<256><<<(BN_ROWS*256 + 255)/256, 256, 0, stream>>>(hmax, hmin, scsh, g4, xc + 256);
    }
    // ------------- layer 5
    {
        float* ss = stats + 4 * 131072;
        k_gemm<<<dim3(16, 128), 256, 0, stream>>>(xc, 512, W5, big, 1024, 512);
        k_stats5<<<dim3(16, 4), 256, 0, stream>>>(big, ss, ss + 65536);
        k_finalize<<<1, 1024, 0, stream>>>(ss, ss + 65536, g5, b5, scsh, 1024, 1.f / (float)BN_ROWS);
        k_seg<<<dim3(128, 4), 256, 0, stream>>>(big, scsh, smax, ssg);
        k_combine<<<dim3(4, 4), 256, 0, stream>>>(smax, ssg, bins);
        k_final<<<252, 256, 0, stream>>>(bins, Wf, bfeat, out);
    }
}

// Round 4
// 908.133 us; speedup vs baseline: 2.1060x; 1.0542x over previous
//
#include <hip/hip_runtime.h>
#include <cstdint>
#include <cstddef>

#define B_SZ   4
#define N_PTS  2048
#define KNN    20
#define BN_ROWS (B_SZ * N_PTS)
#define EPSV   1e-5f
#define SLOPEV 0.2f

// ---------------------------------------------------------------- transpose
__global__ void k_transpose(const float* __restrict__ x, float* __restrict__ xt)
{
    int i = blockIdx.x * 256 + threadIdx.x;
    if (i >= BN_ROWS) return;
    int b = i >> 11, n = i & 2047;
    #pragma unroll
    for (int c = 0; c < 3; ++c)
        xt[i * 3 + c] = x[((b * 3 + c) << 11) + n];
}

// ---------------------------------------------------------------- weight prep
// W (O, 2C) -> Wc (2O, C): rows [0,O)=W1, rows [O,2O)=W2-W1
__global__ void k_prepw(const float* __restrict__ W, float* __restrict__ Wc, int O, int C)
{
    int i = blockIdx.x * 256 + threadIdx.x;
    if (i >= 2 * O * C) return;
    int j = i / C, c = i - j * C;
    float v;
    if (j < O) v = W[j * 2 * C + c];
    else { int jo = j - O; v = W[jo * 2 * C + C + c] - W[jo * 2 * C + c]; }
    Wc[i] = v;
}

// ---------------------------------------------------------------- row norms
__global__ void k_rownorm(const float* __restrict__ xt, int ld, int C, float* __restrict__ xx)
{
    int i = blockIdx.x * 256 + threadIdx.x;
    if (i >= BN_ROWS) return;
    const float* r = xt + (size_t)i * ld;
    float s = 0.f;
    for (int c = 0; c < C; ++c) s = fmaf(r[c], r[c], s);
    xx[i] = s;
}

// ---------------------------------------------------------------- 128x128 GEMM / dist
// DIST=false: C = A(MxK, lda) @ B(NnxK, ldb)^T, C row stride Nn, grid (Nn/128, M/128, 1)
// DIST=true : per batch z: D2[(z*N + i)*N + j] = 2*dot(x_i,x_j) - xx_i - xx_j,
//             A=B=xt (B stride = lda!), grid (16, 16, 2). fma order k-ascending
//             == k_rownorm, so the diagonal is exactly 0.
// Thread tile 8x8 in split 4+4 layout (cols tx*4 and 64+tx*4): every LDS b128
// read is <=2-way bank-conflicted (free), 64 fma per 4 ds_read_b128.
template<bool DIST, bool VEC>
__launch_bounds__(256)
__global__ void k_mm128(const float* __restrict__ A, int lda,
                        const float* __restrict__ Bm, int ldb,
                        const float* __restrict__ xx, int b0,
                        float* __restrict__ Cout, int Nn, int Kd)
{
    constexpr int LDT = 132;            // 128 + 4 floats pad
    __shared__ float As[32 * LDT];
    __shared__ float Bs[32 * LDT];
    const int tid = threadIdx.x;
    const int tx  = tid & 15;
    const int ty  = tid >> 4;
    const int m0  = blockIdx.y * 128;
    const int n0  = blockIdx.x * 128;

    const float* Ab;
    const float* Bb;
    const int ldbe = DIST ? lda : ldb;    // <-- round-3 bug fix: DIST B-stride
    if constexpr (DIST) {
        const int b = b0 + blockIdx.z;
        Ab = A + (size_t)b * N_PTS * lda;
        Bb = Ab;
    } else {
        Ab = A;
        Bb = Bm;
    }

    float acc[2][2][4][4] = {};   // [ih][jh][i][j]

    for (int k0 = 0; k0 < Kd; k0 += 32) {
        // stage A tile (128 rows x 32 k) and B tile, transposed into LDS
        #pragma unroll
        for (int r = 0; r < 4; ++r) {
            int e = r * 256 + tid;          // 0..1023 float4-slots
            int row = e >> 3;               // 0..127
            int kq  = e & 7;                // float4 col
            if constexpr (VEC) {
                float4 v = *(const float4*)&Ab[(size_t)(m0 + row) * lda + k0 + kq * 4];
                As[(kq * 4 + 0) * LDT + row] = v.x;
                As[(kq * 4 + 1) * LDT + row] = v.y;
                As[(kq * 4 + 2) * LDT + row] = v.z;
                As[(kq * 4 + 3) * LDT + row] = v.w;
            } else {
                #pragma unroll
                for (int j = 0; j < 4; ++j) {
                    int kg = k0 + kq * 4 + j;
                    As[(kq * 4 + j) * LDT + row] =
                        (kg < Kd) ? Ab[(size_t)(m0 + row) * lda + kg] : 0.f;
                }
            }
        }
        #pragma unroll
        for (int r = 0; r < 4; ++r) {
            int e = r * 256 + tid;
            int row = e >> 3;
            int kq  = e & 7;
            if constexpr (VEC) {
                float4 v = *(const float4*)&Bb[(size_t)(n0 + row) * ldbe + k0 + kq * 4];
                Bs[(kq * 4 + 0) * LDT + row] = v.x;
                Bs[(kq * 4 + 1) * LDT + row] = v.y;
                Bs[(kq * 4 + 2) * LDT + row] = v.z;
                Bs[(kq * 4 + 3) * LDT + row] = v.w;
            } else {
                #pragma unroll
                for (int j = 0; j < 4; ++j) {
                    int kg = k0 + kq * 4 + j;
                    Bs[(kq * 4 + j) * LDT + row] =
                        (kg < Kd) ? Bb[(size_t)(n0 + row) * ldbe + kg] : 0.f;
                }
            }
        }
        __syncthreads();

        #pragma unroll 8
        for (int kk = 0; kk < 32; ++kk) {
            float4 a0 = *(const float4*)&As[kk * LDT + ty * 4];
            float4 a1 = *(const float4*)&As[kk * LDT + 64 + ty * 4];
            float4 b0v = *(const float4*)&Bs[kk * LDT + tx * 4];
            float4 b1v = *(const float4*)&Bs[kk * LDT + 64 + tx * 4];
            float av[2][4] = {{a0.x, a0.y, a0.z, a0.w}, {a1.x, a1.y, a1.z, a1.w}};
            float bv[2][4] = {{b0v.x, b0v.y, b0v.z, b0v.w}, {b1v.x, b1v.y, b1v.z, b1v.w}};
            #pragma unroll
            for (int ih = 0; ih < 2; ++ih)
                #pragma unroll
                for (int jh = 0; jh < 2; ++jh)
                    #pragma unroll
                    for (int i = 0; i < 4; ++i)
                        #pragma unroll
                        for (int j = 0; j < 4; ++j)
                            acc[ih][jh][i][j] = fmaf(av[ih][i], bv[jh][j], acc[ih][jh][i][j]);
        }
        __syncthreads();
    }

    if constexpr (DIST) {
        const int b = b0 + blockIdx.z;
        const float* xxb = xx + b * N_PTS;
        float xj[2][4];
        #pragma unroll
        for (int jh = 0; jh < 2; ++jh) {
            float4 v = *(const float4*)&xxb[n0 + jh * 64 + tx * 4];
            xj[jh][0] = v.x; xj[jh][1] = v.y; xj[jh][2] = v.z; xj[jh][3] = v.w;
        }
        #pragma unroll
        for (int ih = 0; ih < 2; ++ih)
            #pragma unroll
            for (int i = 0; i < 4; ++i) {
                int row = m0 + ih * 64 + ty * 4 + i;
                float xi = xxb[row];
                size_t base = ((size_t)blockIdx.z * N_PTS + row) * N_PTS;
                #pragma unroll
                for (int jh = 0; jh < 2; ++jh) {
                    float4 v;
                    v.x = 2.f * acc[ih][jh][i][0] - xi - xj[jh][0];
                    v.y = 2.f * acc[ih][jh][i][1] - xi - xj[jh][1];
                    v.z = 2.f * acc[ih][jh][i][2] - xi - xj[jh][2];
                    v.w = 2.f * acc[ih][jh][i][3] - xi - xj[jh][3];
                    *(float4*)&Cout[base + n0 + jh * 64 + tx * 4] = v;
                }
            }
    } else {
        #pragma unroll
        for (int ih = 0; ih < 2; ++ih)
            #pragma unroll
            for (int i = 0; i < 4; ++i) {
                int row = m0 + ih * 64 + ty * 4 + i;
                #pragma unroll
                for (int jh = 0; jh < 2; ++jh) {
                    float4 v = make_float4(acc[ih][jh][i][0], acc[ih][jh][i][1],
                                           acc[ih][jh][i][2], acc[ih][jh][i][3]);
                    *(float4*)&Cout[(size_t)row * Nn + n0 + jh * 64 + tx * 4] = v;
                }
            }
    }
}

// ---------------------------------------------------------------- top-20 select
__launch_bounds__(256)
__global__ void k_select(const float* __restrict__ D2, int b0, int* __restrict__ idx_out)
{
    const int lane = threadIdx.x & 63;
    const int w    = threadIdx.x >> 6;
    const int qloc = blockIdx.x * 4 + w;
    const int bl   = qloc >> 11;
    const int n    = qloc & 2047;
    const float* row = D2 + (size_t)qloc * N_PTS;

    unsigned key[32];
    #pragma unroll
    for (int c = 0; c < 8; ++c) {
        float4 v = *(const float4*)&row[c * 256 + lane * 4];
        float vv[4] = {v.x, v.y, v.z, v.w};
        #pragma unroll
        for (int r = 0; r < 4; ++r) {
            unsigned u = __float_as_uint(vv[r]);
            key[c * 4 + r] = ((int)u >= 0) ? (u | 0x80000000u) : ~u;
        }
    }

    unsigned lo = 0u, hi = 0xFFFFFFFFu;
    while (lo < hi) {
        unsigned mid = lo + ((hi - lo) >> 1);
        int cnt = 0;
        #pragma unroll
        for (int e = 0; e < 32; ++e) cnt += (key[e] > mid) ? 1 : 0;
        #pragma unroll
        for (int s = 32; s >= 1; s >>= 1) cnt += __shfl_xor(cnt, s, 64);
        cnt = __builtin_amdgcn_readfirstlane(cnt);
        if (cnt < KNN) hi = mid; else lo = mid + 1;
    }
    const unsigned T = lo;

    int* outp = idx_out + (size_t)((b0 + bl) * N_PTS + n) * KNN;
    const unsigned long long ltmask = (lane == 0) ? 0ull : (~0ull >> (64 - lane));
    int base = 0;
    #pragma unroll
    for (int e = 0; e < 32; ++e) {
        bool p = key[e] > T;
        unsigned long long m = __ballot(p);
        if (p) {
            int pos = base + __popcll(m & ltmask);
            outp[pos] = (e >> 2) * 256 + lane * 4 + (e & 3);
        }
        base += __popcll(m);
    }
    for (int e = 0; e < 32 && base < KNN; ++e) {
        bool p = key[e] == T;
        unsigned long long m = __ballot(p);
        if (p) {
            int pos = base + __popcll(m & ltmask);
            if (pos < KNN) outp[pos] = (e >> 2) * 256 + lane * 4 + (e & 3);
        }
        base += __popcll(m);
    }
}

// ---------------------------------------------------------------- gather + stats
template<int O, int NSEQ>
__launch_bounds__(256)
__global__ void k_gather(const float* __restrict__ gd, const int* __restrict__ idx,
                         float* __restrict__ hmax, float* __restrict__ hmin,
                         float* __restrict__ ssum, float* __restrict__ ssumsq)
{
    constexpr int NPB = 256 / O;
    const int grp = threadIdx.x / O;
    const int o   = threadIdx.x & (O - 1);
    float accS = 0.f, accS2 = 0.f;
    const int rowsPerBlock = NPB * NSEQ;
    for (int s = 0; s < NSEQ; ++s) {
        int row = blockIdx.x * rowsPerBlock + s * NPB + grp;
        const int* ip = idx + (size_t)row * KNN;
        int bbase = (row >> 11) << 11;
        float gmax = -INFINITY, gmin = INFINITY, gs = 0.f, gs2 = 0.f;
        for (int k = 0; k < KNN; ++k) {
            int nb = ip[k];
            float v = gd[(size_t)(bbase + nb) * (2 * O) + o];
            gmax = fmaxf(gmax, v);
            gmin = fminf(gmin, v);
            gs  += v;
            gs2  = fmaf(v, v, gs2);
        }
        float d = gd[(size_t)row * (2 * O) + O + o];
        hmax[(size_t)row * O + o] = gmax + d;
        hmin[(size_t)row * O + o] = gmin + d;
        accS  += gs + (float)KNN * d;
        accS2 += gs2 + 2.f * d * gs + (float)KNN * d * d;
    }
    int bank = blockIdx.x & 63;
    atomicAdd(&ssum[bank * O + o], accS);
    atomicAdd(&ssumsq[bank * O + o], accS2);
}

// ---------------------------------------------------------------- finalize BN stats
__global__ void k_finalize(const float* __restrict__ ssum, const float* __restrict__ ssumsq,
                           const float* __restrict__ gamma, const float* __restrict__ beta,
                           float* __restrict__ scsh, int O, float invM)
{
    int o = threadIdx.x;
    if (o >= O) return;
    float s = 0.f, s2 = 0.f;
    for (int bk = 0; bk < 64; ++bk) { s += ssum[bk * O + o]; s2 += ssumsq[bk * O + o]; }
    float mean = s * invM;
    float var  = fmaf(-mean, mean, s2 * invM);
    float sc   = gamma[o] * rsqrtf(var + EPSV);
    scsh[o]        = sc;
    scsh[1024 + o] = beta[o] - mean * sc;
}

// ---------------------------------------------------------------- normalize + lrelu -> xc slice
template<int O>
__global__ void k_normalize(const float* __restrict__ hmax, const float* __restrict__ hmin,
                            const float* __restrict__ scsh, const float* __restrict__ gamma,
                            float* __restrict__ xcs)
{
    int i = blockIdx.x * 256 + threadIdx.x;
    if (i >= BN_ROWS * O) return;
    int row = i / O, o = i & (O - 1);
    float h = (gamma[o] >= 0.f) ? hmax[i] : hmin[i];
    float y = fmaf(h, scsh[o], scsh[1024 + o]);
    y = (y >= 0.f) ? y : SLOPEV * y;
    xcs[(size_t)row * 512 + o] = y;
}

// ---------------------------------------------------------------- layer-5 stats
__global__ void k_stats5(const float* __restrict__ h, float* __restrict__ ssum, float* __restrict__ ssumsq)
{
    int o  = blockIdx.y * 256 + threadIdx.x;
    int r0 = blockIdx.x * 512;
    float s = 0.f, s2 = 0.f;
    for (int r = 0; r < 512; ++r) {
        float v = h[(size_t)(r0 + r) * 1024 + o];
        s += v; s2 = fmaf(v, v, s2);
    }
    ssum[blockIdx.x * 1024 + o]   = s;
    ssumsq[blockIdx.x * 1024 + o] = s2;
}

// ---------------------------------------------------------------- normalize+lrelu + 64-seg max/sum
__global__ void k_seg(const float* __restrict__ h, const float* __restrict__ scsh,
                      float* __restrict__ smax, float* __restrict__ ssumseg)
{
    int f   = blockIdx.y * 256 + threadIdx.x;
    int seg = blockIdx.x;
    float sc = scsh[f], sh = scsh[1024 + f];
    float mx = -INFINITY, sm = 0.f;
    int n0 = seg * 64;
    for (int i = 0; i < 64; ++i) {
        float v = fmaf(h[(size_t)(n0 + i) * 1024 + f], sc, sh);
        v = (v >= 0.f) ? v : SLOPEV * v;
        mx = fmaxf(mx, v); sm += v;
    }
    smax[(size_t)seg * 1024 + f]    = mx;
    ssumseg[(size_t)seg * 1024 + f] = sm;
}

// ---------------------------------------------------------------- hierarchical bins
__global__ void k_combine(const float* __restrict__ smax, const float* __restrict__ ssum,
                          float* __restrict__ bins)
{
    int b = blockIdx.x;
    int f = blockIdx.y * 256 + threadIdx.x;
    float mx[32], sm[32];
    #pragma unroll
    for (int s = 0; s < 32; ++s) {
        mx[s] = smax[(size_t)(b * 32 + s) * 1024 + f];
        sm[s] = ssum[(size_t)(b * 32 + s) * 1024 + f];
    }
    float* bb = bins + (size_t)b * 63 * 1024 + f;
    #pragma unroll
    for (int s = 0; s < 32; ++s) bb[(size_t)(31 + s) * 1024] = mx[s] + sm[s] * (1.f / 64.f);
    #pragma unroll
    for (int s = 0; s < 16; ++s) { mx[s] = fmaxf(mx[2*s], mx[2*s+1]); sm[s] = sm[2*s] + sm[2*s+1]; }
    #pragma unroll
    for (int s = 0; s < 16; ++s) bb[(size_t)(15 + s) * 1024] = mx[s] + sm[s] * (1.f / 128.f);
    #pragma unroll
    for (int s = 0; s < 8; ++s)  { mx[s] = fmaxf(mx[2*s], mx[2*s+1]); sm[s] = sm[2*s] + sm[2*s+1]; }
    #pragma unroll
    for (int s = 0; s < 8; ++s)  bb[(size_t)(7 + s) * 1024] = mx[s] + sm[s] * (1.f / 256.f);
    #pragma unroll
    for (int s = 0; s < 4; ++s)  { mx[s] = fmaxf(mx[2*s], mx[2*s+1]); sm[s] = sm[2*s] + sm[2*s+1]; }
    #pragma unroll
    for (int s = 0; s < 4; ++s)  bb[(size_t)(3 + s) * 1024] = mx[s] + sm[s] * (1.f / 512.f);
    #pragma unroll
    for (int s = 0; s < 2; ++s)  { mx[s] = fmaxf(mx[2*s], mx[2*s+1]); sm[s] = sm[2*s] + sm[2*s+1]; }
    #pragma unroll
    for (int s = 0; s < 2; ++s)  bb[(size_t)(1 + s) * 1024] = mx[s] + sm[s] * (1.f / 1024.f);
    mx[0] = fmaxf(mx[0], mx[1]); sm[0] = sm[0] + sm[1];
    bb[0] = mx[0] + sm[0] * (1.f / 2048.f);
}

// ---------------------------------------------------------------- final projection
__launch_bounds__(256)
__global__ void k_final(const float* __restrict__ bins, const float* __restrict__ Wf,
                        const float* __restrict__ bfeat, float* __restrict__ out)
{
    __shared__ float row[1024];
    int sb = blockIdx.x;
    int s = sb >> 2, b = sb & 3;
    for (int e = threadIdx.x; e < 1024; e += 256)
        row[e] = bins[(size_t)(b * 63 + s) * 1024 + e];
    __syncthreads();
    int o = threadIdx.x;
    const float* w = Wf + (size_t)o * 1024;
    float acc = 0.f;
    for (int fb = 0; fb < 1024; fb += 4) {
        float4 w4 = *(const float4*)&w[fb];
        acc = fmaf(row[fb + 0], w4.x, acc);
        acc = fmaf(row[fb + 1], w4.y, acc);
        acc = fmaf(row[fb + 2], w4.z, acc);
        acc = fmaf(row[fb + 3], w4.w, acc);
    }
    out[(size_t)sb * 256 + o] = acc + bfeat[o];
}

// ================================================================ launch
extern "C" void kernel_launch(void* const* d_in, const int* in_sizes, int n_in,
                              void* d_out, int out_size, void* d_ws, size_t ws_size,
                              hipStream_t stream)
{
    const float* x  = (const float*)d_in[0];
    const float* W1 = (const float*)d_in[1];
    const float* g1 = (const float*)d_in[2];
    const float* b1 = (const float*)d_in[3];
    const float* W2 = (const float*)d_in[4];
    const float* g2 = (const float*)d_in[5];
    const float* b2 = (const float*)d_in[6];
    const float* W3 = (const float*)d_in[7];
    const float* g3 = (const float*)d_in[8];
    const float* b3 = (const float*)d_in[9];
    const float* W4 = (const float*)d_in[10];
    const float* g4 = (const float*)d_in[11];
    const float* b4 = (const float*)d_in[12];
    const float* W5 = (const float*)d_in[13];
    const float* g5 = (const float*)d_in[14];
    const float* b5 = (const float*)d_in[15];
    const float* Wf = (const float*)d_in[16];
    const float* bfeat = (const float*)d_in[17];
    float* out = (float*)d_out;
    float* ws  = (float*)d_ws;

    // workspace layout (floats) — 72.9 MB total, unchanged.
    float* xt1   = ws;                        // 24576
    int*   idx   = (int*)(ws + 24576);        // 163840
    float* xx    = ws + 24576 + 163840;       // 8192
    float* xc    = xx + 8192;                 // 8192*512
    float* hmax  = xc + 4194304;              // 8192*256
    float* hmin  = hmax + 2097152;            // 8192*256
    float* stats = hmin + 2097152;            // 5 * 2 * 64 * 1024
    float* scsh  = stats + 655360;            // 2048
    float* smax  = scsh + 2048;               // 128*1024
    float* ssg   = smax + 131072;             // 128*1024
    float* bins  = ssg + 131072;              // 4*63*1024
    float* wcomb = bins + 258048;             // 512*128 max
    float* big   = wcomb + 65536;             // 8,388,608 floats

    hipMemsetAsync(stats, 0, 655360 * sizeof(float), stream);

    k_transpose<<<32, 256, 0, stream>>>(x, xt1);

    const float invMk = 1.f / (float)(BN_ROWS * KNN);

    // ------------- layer 1: C=3, O=64
    {
        float* ss = stats + 0 * 131072;
        k_prepw<<<(2*64*3 + 255)/256, 256, 0, stream>>>(W1, wcomb, 64, 3);
        k_rownorm<<<32, 256, 0, stream>>>(xt1, 3, 3, xx);
        for (int c = 0; c < 2; ++c) {
            k_mm128<true, false><<<dim3(16, 16, 2), 256, 0, stream>>>(xt1, 3, nullptr, 0, xx, 2*c, big, N_PTS, 3);
            k_select<<<1024, 256, 0, stream>>>(big, 2*c, idx);
        }
        k_mm128<false, false><<<dim3(1, 64, 1), 256, 0, stream>>>(xt1, 3, wcomb, 3, nullptr, 0, big, 128, 3);
        k_gather<64, 8><<<256, 256, 0, stream>>>(big, idx, hmax, hmin, ss, ss + 65536);
        k_finalize<<<1, 64, 0, stream>>>(ss, ss + 65536, g1, b1, scsh, 64, invMk);
        k_normalize<64><<<(BN_ROWS*64 + 255)/256, 256, 0, stream>>>(hmax, hmin, scsh, g1, xc + 0);
    }
    // ------------- layer 2: C=64, O=64
    {
        float* ss = stats + 1 * 131072;
        k_prepw<<<(2*64*64 + 255)/256, 256, 0, stream>>>(W2, wcomb, 64, 64);
        k_rownorm<<<32, 256, 0, stream>>>(xc + 0, 512, 64, xx);
        for (int c = 0; c < 2; ++c) {
            k_mm128<true, true><<<dim3(16, 16, 2), 256, 0, stream>>>(xc + 0, 512, nullptr, 0, xx, 2*c, big, N_PTS, 64);
            k_select<<<1024, 256, 0, stream>>>(big, 2*c, idx);
        }
        k_mm128<false, true><<<dim3(1, 64, 1), 256, 0, stream>>>(xc + 0, 512, wcomb, 64, nullptr, 0, big, 128, 64);
        k_gather<64, 8><<<256, 256, 0, stream>>>(big, idx, hmax, hmin, ss, ss + 65536);
        k_finalize<<<1, 64, 0, stream>>>(ss, ss + 65536, g2, b2, scsh, 64, invMk);
        k_normalize<64><<<(BN_ROWS*64 + 255)/256, 256, 0, stream>>>(hmax, hmin, scsh, g2, xc + 64);
    }
    // ------------- layer 3: C=64, O=128
    {
        float* ss = stats + 2 * 131072;
        k_prepw<<<(2*128*64 + 255)/256, 256, 0, stream>>>(W3, wcomb, 128, 64);
        k_rownorm<<<32, 256, 0, stream>>>(xc + 64, 512, 64, xx);
        for (int c = 0; c < 2; ++c) {
            k_mm128<true, true><<<dim3(16, 16, 2), 256, 0, stream>>>(xc + 64, 512, nullptr, 0, xx, 2*c, big, N_PTS, 64);
            k_select<<<1024, 256, 0, stream>>>(big, 2*c, idx);
        }
        k_mm128<false, true><<<dim3(2, 64, 1), 256, 0, stream>>>(xc + 64, 512, wcomb, 64, nullptr, 0, big, 256, 64);
        k_gather<128, 8><<<512, 256, 0, stream>>>(big, idx, hmax, hmin, ss, ss + 65536);
        k_finalize<<<1, 128, 0, stream>>>(ss, ss + 65536, g3, b3, scsh, 128, invMk);
        k_normalize<128><<<(BN_ROWS*128 + 255)/256, 256, 0, stream>>>(hmax, hmin, scsh, g3, xc + 128);
    }
    // ------------- layer 4: C=128, O=256
    {
        float* ss = stats + 3 * 131072;
        k_prepw<<<(2*256*128 + 255)/256, 256, 0, stream>>>(W4, wcomb, 256, 128);
        k_rownorm<<<32, 256, 0, stream>>>(xc + 128, 512, 128, xx);
        for (int c = 0; c < 2; ++c) {
            k_mm128<true, true><<<dim3(16, 16, 2), 256, 0, stream>>>(xc + 128, 512, nullptr, 0, xx, 2*c, big, N_PTS, 128);
            k_select<<<1024, 256, 0, stream>>>(big, 2*c, idx);
        }
        k_mm128<false, true><<<dim3(4, 64, 1), 256, 0, stream>>>(xc + 128, 512, wcomb, 128, nullptr, 0, big, 512, 128);
        k_gather<256, 8><<<1024, 256, 0, stream>>>(big, idx, hmax, hmin, ss, ss + 65536);
        k_finalize<<<1, 256, 0, stream>>>(ss, ss + 65536, g4, b4, scsh, 256, invMk);
        k_normalize<256><<<(BN_ROWS*256 + 255)/256, 256, 0, stream>>>(hmax, hmin, scsh, g4, xc + 256);
    }
    // ------------- layer 5
    {
        float* ss = stats + 4 * 131072;
        k_mm128<false, true><<<dim3(8, 64, 1), 256, 0, stream>>>(xc, 512, W5, 512, nullptr, 0, big, 1024, 512);
        k_stats5<<<dim3(16, 4), 256, 0, stream>>>(big, ss, ss + 65536);
        k_finalize<<<1, 1024, 0, stream>>>(ss, ss + 65536, g5, b5, scsh, 1024, 1.f / (float)BN_ROWS);
        k_seg<<<dim3(128, 4), 256, 0, stream>>>(big, scsh, smax, ssg);
        k_combine<<<dim3(4, 4), 256, 0, stream>>>(smax, ssg, bins);
        k_final<<<252, 256, 0, stream>>>(bins, Wf, bfeat, out);
    }
}